// Round 4
// baseline (389.462 us; speedup 1.0000x reference)
//
#include <hip/hip_runtime.h>
#include <math.h>

typedef short short8 __attribute__((ext_vector_type(8)));
typedef float f32x4 __attribute__((ext_vector_type(4)));

#define B_ 16
#define TQ_ 64
#define TK_ 512
#define D_ 256
#define V_ 32000
#define M_ (B_ * TQ_)   // 1024 rows

__device__ __forceinline__ unsigned short f2bf(float x) {
    unsigned int u = __float_as_uint(x);
    unsigned int r = (u + 0x7fffu + ((u >> 16) & 1u)) >> 16;
    return (unsigned short)r;
}
__device__ __forceinline__ float bf2f(unsigned short u) {
    return __uint_as_float((unsigned int)u << 16);
}

__device__ __forceinline__ void gload_lds16(const void* g, void* l) {
    __builtin_amdgcn_global_load_lds(
        (const __attribute__((address_space(1))) void*)g,
        (__attribute__((address_space(3))) void*)l, 16, 0, 0);
}

// ---------------- dedup: per-batch leader/next chains, branch-free scans ----------------
__global__ __launch_bounds__(256) void dedup_kernel(
    const int* __restrict__ cp, int* __restrict__ nexta, int* __restrict__ leader)
{
    __shared__ __align__(16) int c[TK_];
    const int b = blockIdx.x >> 1, half = blockIdx.x & 1, tid = threadIdx.x;
    c[tid] = cp[b * TK_ + tid];
    c[tid + 256] = cp[b * TK_ + 256 + tid];
    __syncthreads();
    const int k = half * 256 + tid;
    const int v = c[k];
    int fm = 1024, nx = 1024;
#pragma unroll 8
    for (int j0 = 0; j0 < TK_; j0 += 4) {
        const int4 q = *(const int4*)&c[j0];
        if (q.x == v) { fm = min(fm, j0);     if (j0     > k) nx = min(nx, j0);     }
        if (q.y == v) { fm = min(fm, j0 + 1); if (j0 + 1 > k) nx = min(nx, j0 + 1); }
        if (q.z == v) { fm = min(fm, j0 + 2); if (j0 + 2 > k) nx = min(nx, j0 + 2); }
        if (q.w == v) { fm = min(fm, j0 + 3); if (j0 + 3 > k) nx = min(nx, j0 + 3); }
    }
    nexta[b * TK_ + k] = (nx < 1024) ? nx : -1;
    leader[b * TK_ + k] = (fm == k) ? 1 : 0;
}

// ---------------- convert out_states f32 -> bf16 (row-major [1024][256]) ----------------
__global__ __launch_bounds__(256) void conv_a_kernel(
    const float* __restrict__ A, unsigned short* __restrict__ Ab)
{
    const int i = (blockIdx.x * 256 + threadIdx.x) * 4;
    const float4 v = *(const float4*)&A[i];
    ushort4 o;
    o.x = f2bf(v.x); o.y = f2bf(v.y); o.z = f2bf(v.z); o.w = f2bf(v.w);
    *(ushort4*)&Ab[i] = o;
}

// ---------------- convert + transpose W_state [256][32000] f32 -> Wt [32000][256] bf16 ----
__global__ __launch_bounds__(256) void conv_w_kernel(
    const float* __restrict__ W, unsigned short* __restrict__ Wt)
{
    __shared__ float tile[64][65];
    const int tid = threadIdx.x;
    const int k0 = (blockIdx.x & 3) * 64;
    const int n0 = (blockIdx.x >> 2) * 64;
#pragma unroll
    for (int i = 0; i < 16; i++) {
        const int r = i * 4 + (tid >> 6), cc = tid & 63;
        tile[r][cc] = W[(k0 + r) * V_ + n0 + cc];
    }
    __syncthreads();
#pragma unroll
    for (int i = 0; i < 4; i++) {
        const int nl = i * 16 + (tid >> 4);
        const int kq = (tid & 15) * 4;
        ushort4 o;
        o.x = f2bf(tile[kq + 0][nl]);
        o.y = f2bf(tile[kq + 1][nl]);
        o.z = f2bf(tile[kq + 2][nl]);
        o.w = f2bf(tile[kq + 3][nl]);
        *(ushort4*)&Wt[(n0 + nl) * D_ + k0 + kq] = o;
    }
}

// ---------------- convert+transpose context -> Ct bf16 [b][256 d][512 k] ----------------
__global__ __launch_bounds__(256) void conv_ct_kernel(
    const float* __restrict__ ctx, unsigned short* __restrict__ Ct)
{
    __shared__ float tile[64][65];
    const int tid = threadIdx.x;
    const int b = blockIdx.x >> 5;
    const int r5 = blockIdx.x & 31;
    const int k0 = (r5 >> 2) * 64;
    const int d0 = (r5 & 3) * 64;
#pragma unroll
    for (int i = 0; i < 16; i++) {
        const int r = i * 4 + (tid >> 6), cc = tid & 63;
        tile[r][cc] = ctx[((b * TK_) + k0 + r) * D_ + d0 + cc];
    }
    __syncthreads();
#pragma unroll
    for (int i = 0; i < 4; i++) {
        const int dl = i * 16 + (tid >> 4);
        const int kq = (tid & 15) * 4;
        ushort4 o;
        o.x = f2bf(tile[kq + 0][dl]);
        o.y = f2bf(tile[kq + 1][dl]);
        o.z = f2bf(tile[kq + 2][dl]);
        o.w = f2bf(tile[kq + 3][dl]);
        *(ushort4*)&Ct[((b * D_) + d0 + dl) * TK_ + k0 + kq] = o;
    }
}

// ---------------- QK^T: S[b] = Ab[b] (bf16) @ context[b]^T (f32, converted) * scale -----
// BM=64, BN=64, BK=64; 4 waves 2x2, wave tile 32x32 = 2x2 of 16x16x32.
__global__ __launch_bounds__(256) void gemm_qk(
    const unsigned short* __restrict__ Ab, const float* __restrict__ ctx,
    float* __restrict__ S)
{
    __shared__ short Al[64][72];
    __shared__ short Bl[64][72];
    const int tid = threadIdx.x;
    const int b = blockIdx.x >> 3;
    const int n0 = (blockIdx.x & 7) * 64;
    const unsigned short* A = Ab + (size_t)b * 64 * D_;
    const float* Bt = ctx + (size_t)b * TK_ * D_;
    float* C = S + (size_t)b * 64 * TK_;

    const int wid = tid >> 6, lane = tid & 63;
    const int wm = wid & 1, wn = wid >> 1;
    const int quad = lane >> 4, l15 = lane & 15;

    f32x4 acc[2][2];
#pragma unroll
    for (int i = 0; i < 2; i++)
#pragma unroll
        for (int j = 0; j < 2; j++) acc[i][j] = f32x4{0.f, 0.f, 0.f, 0.f};

    for (int k0 = 0; k0 < D_; k0 += 64) {
        __syncthreads();
#pragma unroll
        for (int i = 0; i < 2; i++) {
            const int c = tid + i * 256;
            const int r = c >> 3, kc = (c & 7) * 8;
            *(uint4*)&Al[r][kc] = *(const uint4*)&A[r * D_ + k0 + kc];
        }
#pragma unroll
        for (int i = 0; i < 4; i++) {
            const int c = tid + i * 256;
            const int r = c >> 4, kc = (c & 15) * 4;
            const float4 v = *(const float4*)&Bt[(size_t)(n0 + r) * D_ + k0 + kc];
            ushort4 o;
            o.x = f2bf(v.x); o.y = f2bf(v.y); o.z = f2bf(v.z); o.w = f2bf(v.w);
            *(ushort4*)&Bl[r][kc] = o;
        }
        __syncthreads();
#pragma unroll
        for (int ks = 0; ks < 64; ks += 32) {
            short8 af[2], bf[2];
#pragma unroll
            for (int mt = 0; mt < 2; mt++)
                af[mt] = *(const short8*)&Al[wm * 32 + mt * 16 + l15][ks + quad * 8];
#pragma unroll
            for (int nt = 0; nt < 2; nt++)
                bf[nt] = *(const short8*)&Bl[wn * 32 + nt * 16 + l15][ks + quad * 8];
#pragma unroll
            for (int mt = 0; mt < 2; mt++)
#pragma unroll
                for (int nt = 0; nt < 2; nt++)
                    acc[mt][nt] = __builtin_amdgcn_mfma_f32_16x16x32_bf16(
                        af[mt], bf[nt], acc[mt][nt], 0, 0, 0);
        }
    }
#pragma unroll
    for (int mt = 0; mt < 2; mt++)
#pragma unroll
        for (int nt = 0; nt < 2; nt++)
#pragma unroll
            for (int r = 0; r < 4; r++) {
                const int rl = wm * 32 + mt * 16 + quad * 4 + r;
                const int col = n0 + wn * 32 + nt * 16 + l15;
                C[rl * TK_ + col] = acc[mt][nt][r] * 0.0625f;
            }
}

// ---------------- PV: cv[b] = Pb[b] (bf16) @ Ct[b]^T (bf16) -----------------------------
__global__ __launch_bounds__(256) void gemm_pv(
    const unsigned short* __restrict__ Pb, const unsigned short* __restrict__ Ctg,
    float* __restrict__ cv)
{
    __shared__ short Al[64][72];
    __shared__ short Bl[64][72];
    const int tid = threadIdx.x;
    const int b = blockIdx.x >> 2;
    const int n0 = (blockIdx.x & 3) * 64;
    const unsigned short* A = Pb + (size_t)b * 64 * TK_;
    const unsigned short* Bt = Ctg + (size_t)b * D_ * TK_;
    float* C = cv + (size_t)b * 64 * D_;

    const int wid = tid >> 6, lane = tid & 63;
    const int wm = wid & 1, wn = wid >> 1;
    const int quad = lane >> 4, l15 = lane & 15;

    f32x4 acc[2][2];
#pragma unroll
    for (int i = 0; i < 2; i++)
#pragma unroll
        for (int j = 0; j < 2; j++) acc[i][j] = f32x4{0.f, 0.f, 0.f, 0.f};

    for (int k0 = 0; k0 < TK_; k0 += 64) {
        __syncthreads();
#pragma unroll
        for (int i = 0; i < 2; i++) {
            const int c = tid + i * 256;
            const int r = c >> 3, kc = (c & 7) * 8;
            *(uint4*)&Al[r][kc] = *(const uint4*)&A[(size_t)r * TK_ + k0 + kc];
        }
#pragma unroll
        for (int i = 0; i < 2; i++) {
            const int c = tid + i * 256;
            const int r = c >> 3, kc = (c & 7) * 8;
            *(uint4*)&Bl[r][kc] = *(const uint4*)&Bt[(size_t)(n0 + r) * TK_ + k0 + kc];
        }
        __syncthreads();
#pragma unroll
        for (int ks = 0; ks < 64; ks += 32) {
            short8 af[2], bf[2];
#pragma unroll
            for (int mt = 0; mt < 2; mt++)
                af[mt] = *(const short8*)&Al[wm * 32 + mt * 16 + l15][ks + quad * 8];
#pragma unroll
            for (int nt = 0; nt < 2; nt++)
                bf[nt] = *(const short8*)&Bl[wn * 32 + nt * 16 + l15][ks + quad * 8];
#pragma unroll
            for (int mt = 0; mt < 2; mt++)
#pragma unroll
                for (int nt = 0; nt < 2; nt++)
                    acc[mt][nt] = __builtin_amdgcn_mfma_f32_16x16x32_bf16(
                        af[mt], bf[nt], acc[mt][nt], 0, 0, 0);
        }
    }
#pragma unroll
    for (int mt = 0; mt < 2; mt++)
#pragma unroll
        for (int nt = 0; nt < 2; nt++)
#pragma unroll
            for (int r = 0; r < 4; r++) {
                const int rl = wm * 32 + mt * 16 + quad * 4 + r;
                const int col = n0 + wn * 32 + nt * 16 + l15;
                C[rl * D_ + col] = acc[mt][nt][r];
            }
}

// ---------------- softmax over S rows; write attn f32 in-place + P bf16 ----------------
__global__ __launch_bounds__(256) void softmax_kernel(
    float* __restrict__ S, unsigned short* __restrict__ Pb)
{
    const int w = threadIdx.x >> 6, lane = threadIdx.x & 63;
    const int row = blockIdx.x * 4 + w;
    float v[8], m = -1e30f;
#pragma unroll
    for (int j = 0; j < 8; j++) { v[j] = S[row * TK_ + lane + 64 * j]; m = fmaxf(m, v[j]); }
#pragma unroll
    for (int off = 32; off; off >>= 1) m = fmaxf(m, __shfl_xor(m, off));
    float s = 0.f;
#pragma unroll
    for (int j = 0; j < 8; j++) { v[j] = __expf(v[j] - m); s += v[j]; }
#pragma unroll
    for (int off = 32; off; off >>= 1) s += __shfl_xor(s, off);
    const float inv = 1.0f / s;
#pragma unroll
    for (int j = 0; j < 8; j++) {
        const float p = v[j] * inv;
        S[row * TK_ + lane + 64 * j] = p;
        Pb[row * TK_ + lane + 64 * j] = f2bf(p);
    }
}

// ---------------- p_gen ----------------
__global__ __launch_bounds__(256) void pgen_kernel(
    const float* __restrict__ os, const float* __restrict__ cv,
    const float* __restrict__ dm, const float* __restrict__ W_gen,
    const float* __restrict__ b_gen, float* __restrict__ pg)
{
    const int w = threadIdx.x >> 6, lane = threadIdx.x & 63;
    const int row = blockIdx.x * 4 + w;
    const int d4 = lane * 4;
    const float4 o4 = *(const float4*)&os[row * D_ + d4];
    const float4 c4 = *(const float4*)&cv[row * D_ + d4];
    const float4 m4 = *(const float4*)&dm[row * D_ + d4];
    const float4 w0 = *(const float4*)&W_gen[d4];
    const float4 w1 = *(const float4*)&W_gen[D_ + d4];
    const float4 w2 = *(const float4*)&W_gen[2 * D_ + d4];
    float p = o4.x * w0.x + o4.y * w0.y + o4.z * w0.z + o4.w * w0.w
            + c4.x * w1.x + c4.y * w1.y + c4.z * w1.z + c4.w * w1.w
            + m4.x * w2.x + m4.y * w2.y + m4.z * w2.z + m4.w * w2.w;
#pragma unroll
    for (int off = 32; off; off >>= 1) p += __shfl_xor(p, off);
    if (lane == 0) pg[row] = 1.0f / (1.0f + __expf(-(p + b_gen[0])));
}

// ---------------- fused vocab GEMM with XOR-swizzled LDS ----------------
// BM=BN=128, BK=64, 4 waves (2x2), wave tile 64x64 = 4x4 16x16x32 mfma.
// LDS physical chunk p (16B) of row r holds logical k-chunk p^(r&7); readers
// use pc = (ks/8+quad)^(l15&7) -> 2-way bank aliasing only (free).
// BF16=1: store bf16 logits to Lb; BF16=0: store f32 logits to Fout.
template <int BF16>
__global__ __launch_bounds__(256) void gemm_vocab_fused(
    const unsigned short* __restrict__ A,   // [1024][256] bf16
    const unsigned short* __restrict__ Bt,  // [32000][256] bf16
    const float* __restrict__ b_state,
    float* __restrict__ Z,
    unsigned short* __restrict__ Lb,
    float* __restrict__ Fout)
{
    __shared__ short Al[128][64];   // 16 KB, swizzled
    __shared__ short Bl[128][64];   // 16 KB, swizzled
    __shared__ float bst[128];

    const int tid = threadIdx.x;
    const int bx = blockIdx.x;
    const int m0 = (bx & 7) * 128;
    const int n0 = (bx >> 3) * 128;

    if (tid < 128) bst[tid] = b_state[n0 + tid];

    const int wid = tid >> 6, lane = tid & 63;
    const int wm = wid & 1, wn = wid >> 1;
    const int quad = lane >> 4, l15 = lane & 15;
    const int h = l15 & 7;

    f32x4 acc[4][4];
#pragma unroll
    for (int i = 0; i < 4; i++)
#pragma unroll
        for (int j = 0; j < 4; j++) acc[i][j] = f32x4{0.f, 0.f, 0.f, 0.f};

    for (int k0 = 0; k0 < D_; k0 += 64) {
        __syncthreads();
#pragma unroll
        for (int i = 0; i < 4; i++) {
            const int cid = (i * 4 + wid) * 64 + lane;
            const int r = cid >> 3;
            const int clog = (cid & 7) ^ (r & 7);
            gload_lds16(&A[(size_t)(m0 + r) * D_ + k0 + clog * 8],
                        &Al[0][0] + (i * 4 + wid) * 512);
        }
#pragma unroll
        for (int i = 0; i < 4; i++) {
            const int cid = (i * 4 + wid) * 64 + lane;
            const int r = cid >> 3;
            const int clog = (cid & 7) ^ (r & 7);
            gload_lds16(&Bt[(size_t)(n0 + r) * D_ + k0 + clog * 8],
                        &Bl[0][0] + (i * 4 + wid) * 512);
        }
        __syncthreads();
#pragma unroll
        for (int ks = 0; ks < 64; ks += 32) {
            const int cbase = ks >> 3;
            short8 af[4], bf[4];
#pragma unroll
            for (int mt = 0; mt < 4; mt++) {
                const int pc = (cbase + quad) ^ h;
                af[mt] = *(const short8*)&Al[wm * 64 + mt * 16 + l15][pc * 8];
            }
#pragma unroll
            for (int nt = 0; nt < 4; nt++) {
                const int pc = (cbase + quad) ^ h;
                bf[nt] = *(const short8*)&Bl[wn * 64 + nt * 16 + l15][pc * 8];
            }
#pragma unroll
            for (int mt = 0; mt < 4; mt++)
#pragma unroll
                for (int nt = 0; nt < 4; nt++)
                    acc[mt][nt] = __builtin_amdgcn_mfma_f32_16x16x32_bf16(
                        af[mt], bf[nt], acc[mt][nt], 0, 0, 0);
        }
    }

#pragma unroll
    for (int mt = 0; mt < 4; mt++) {
        float rs[4] = {0.f, 0.f, 0.f, 0.f};
#pragma unroll
        for (int nt = 0; nt < 4; nt++) {
            const float bcol = bst[wn * 64 + nt * 16 + l15];
#pragma unroll
            for (int r = 0; r < 4; r++) {
                const int row = wm * 64 + mt * 16 + quad * 4 + r;
                const int col = wn * 64 + nt * 16 + l15;
                const float v = acc[mt][nt][r] + bcol;
                if (BF16)
                    Lb[(size_t)(m0 + row) * V_ + n0 + col] = f2bf(v);
                else
                    Fout[(size_t)(m0 + row) * V_ + n0 + col] = v;
                rs[r] += __expf(v);
            }
        }
#pragma unroll
        for (int r = 0; r < 4; r++) {
            float v = rs[r];
            v += __shfl_xor(v, 1);
            v += __shfl_xor(v, 2);
            v += __shfl_xor(v, 4);
            v += __shfl_xor(v, 8);
            if (l15 == 0)
                atomicAdd(&Z[m0 + wm * 64 + mt * 16 + quad * 4 + r], v);
        }
    }
}

// ---------------- fused epilogue: rc + dense add + sparse pointer fixup, per row --------
template <int BF16>
__global__ __launch_bounds__(256) void epilogue_fused(
    const unsigned short* __restrict__ Lb,
    const float* __restrict__ pg, const float* __restrict__ Z,
    const int* __restrict__ cp, const int* __restrict__ nexta,
    const int* __restrict__ leader, const float* __restrict__ attn,
    float* __restrict__ out)
{
    const int row = blockIdx.x, tid = threadIdx.x;
    const float pgr = pg[row];
    const float rc = logf(pgr) - logf(Z[row]);
    float* orow = out + (size_t)row * V_;
    if (BF16) {
        const unsigned short* lrow = Lb + (size_t)row * V_;
        for (int i = tid; i < V_ / 8; i += 256) {
            const ushort4 u0 = *(const ushort4*)&lrow[i * 8];
            const ushort4 u1 = *(const ushort4*)&lrow[i * 8 + 4];
            float4 f0, f1;
            f0.x = bf2f(u0.x) + rc; f0.y = bf2f(u0.y) + rc;
            f0.z = bf2f(u0.z) + rc; f0.w = bf2f(u0.w) + rc;
            f1.x = bf2f(u1.x) + rc; f1.y = bf2f(u1.y) + rc;
            f1.z = bf2f(u1.z) + rc; f1.w = bf2f(u1.w) + rc;
            *(float4*)&orow[i * 8] = f0;
            *(float4*)&orow[i * 8 + 4] = f1;
        }
    } else {
        for (int i = tid; i < V_ / 4; i += 256) {
            float4 v = *(float4*)&orow[i * 4];
            v.x += rc; v.y += rc; v.z += rc; v.w += rc;
            *(float4*)&orow[i * 4] = v;
        }
    }
    __syncthreads();
    const int b = row >> 6;
    for (int k = tid; k < TK_; k += 256) {
        if (!leader[b * TK_ + k]) continue;
        float a = attn[(size_t)row * TK_ + k];
        int j = nexta[b * TK_ + k];
        while (j >= 0) { a += attn[(size_t)row * TK_ + j]; j = nexta[b * TK_ + j]; }
        const float val = (1.0f - pgr) * a;
        const int v = cp[b * TK_ + k];
        float base;
        if (BF16) base = bf2f(Lb[(size_t)row * V_ + v]) + rc;
        else      base = orow[v];   // already includes rc (post-barrier read)
        orow[v] = logf(__expf(base) + val);
    }
}

extern "C" void kernel_launch(void* const* d_in, const int* in_sizes, int n_in,
                              void* d_out, int out_size, void* d_ws, size_t ws_size,
                              hipStream_t stream)
{
    const float* domainslots = (const float*)d_in[0];
    const float* out_states  = (const float*)d_in[1];
    const float* context     = (const float*)d_in[2];
    const int*   cp          = (const int*)d_in[3];
    const float* W_state     = (const float*)d_in[4];
    const float* b_state     = (const float*)d_in[5];
    const float* W_gen       = (const float*)d_in[6];
    const float* b_gen       = (const float*)d_in[7];
    float* out = (float*)d_out;
    char* ws = (char*)d_ws;

    // workspace layout (bytes)
    float* Z      = (float*)(ws);                           // 0        (4 KB)
    float* pg     = (float*)(ws + 4096);                    // 4 KB
    float* S      = (float*)(ws + 8192);                    // 2 MB (scores->attn in place)
    int* nexta    = (int*)(ws + 2105344);                   // 32 KB
    int* leader   = (int*)(ws + 2138112);                   // 32 KB
    unsigned short* Ab = (unsigned short*)(ws + 2170880);   // 512 KB
    unsigned short* Wt = (unsigned short*)(ws + 2695168);   // 16.4 MB
    unsigned short* Ct = (unsigned short*)(ws + 19079168);  // 4 MB
    unsigned short* Pb = (unsigned short*)(ws + 23273472);  // 1 MB
    float* cv     = (float*)(ws + 24322048);                // 1 MB
    unsigned short* Lb = (unsigned short*)(ws + 25370624);  // 65.5 MB -> end 90,906,624
    const bool use_lb = (ws_size >= (size_t)90906624);

    hipMemsetAsync(Z, 0, M_ * sizeof(float), stream);
    dedup_kernel<<<B_ * 2, 256, 0, stream>>>(cp, nexta, leader);
    conv_a_kernel<<<(M_ * D_) / 1024, 256, 0, stream>>>(out_states, Ab);
    conv_w_kernel<<<(D_ / 64) * (V_ / 64), 256, 0, stream>>>(W_state, Wt);
    conv_ct_kernel<<<B_ * 32, 256, 0, stream>>>(context, Ct);

    gemm_qk<<<B_ * 8, 256, 0, stream>>>(Ab, context, S);
    softmax_kernel<<<M_ / 4, 256, 0, stream>>>(S, Pb);
    gemm_pv<<<B_ * 4, 256, 0, stream>>>(Pb, Ct, cv);
    pgen_kernel<<<M_ / 4, 256, 0, stream>>>(out_states, cv, domainslots, W_gen, b_gen, pg);

    if (use_lb) {
        gemm_vocab_fused<1><<<(M_ / 128) * (V_ / 128), 256, 0, stream>>>(
            Ab, Wt, b_state, Z, Lb, out);
        epilogue_fused<1><<<M_, 256, 0, stream>>>(Lb, pg, Z, cp, nexta, leader, S, out);
    } else {
        gemm_vocab_fused<0><<<(M_ / 128) * (V_ / 128), 256, 0, stream>>>(
            Ab, Wt, b_state, Z, Lb, out);
        epilogue_fused<0><<<M_, 256, 0, stream>>>(Lb, pg, Z, cp, nexta, leader, S, out);
    }
}